// Round 20
// baseline (407.476 us; speedup 1.0000x reference)
//
#include <hip/hip_runtime.h>
#include <hip/hip_bf16.h>

using bf16 = __hip_bfloat16;

typedef __attribute__((ext_vector_type(4))) float f32x4;
typedef __attribute__((ext_vector_type(8))) short short8;

typedef const void __attribute__((address_space(1)))* gas1_t;
typedef void __attribute__((address_space(3)))* las3_t;
#define GLDS(gp, lp) __builtin_amdgcn_global_load_lds((gas1_t)(gp), (las3_t)(lp), 16, 0, 0)

__device__ inline short f2bfbits(float f) {
  union { bf16 h; short s; } u;
  u.h = __float2bfloat16(f);
  return u.s;
}
__device__ inline float bf2f(short u) {
  unsigned x = ((unsigned)(unsigned short)u) << 16;
  float f; __builtin_memcpy(&f, &x, 4); return f;
}

__device__ inline void store_out(float* C, size_t idx, float v) { C[idx] = v; }
__device__ inline void store_out(bf16* C, size_t idx, float v) { C[idx] = __float2bfloat16(v); }

// ---------------------------------------------------------------------------
// ROUND-15 gemm256 VERBATIM: 256x256, BK=32, 8 waves, 3-ring LDS + counted
// vmcnt(4), chunk-XOR swizzle. MODE 0: plain; MODE 1: causal S -> tri grid,
// 256-packed tri bf16 out.
// ---------------------------------------------------------------------------
template<typename TOUT, int MODE>
__global__ __launch_bounds__(512, 2) void gemm256(
    const short* __restrict__ A, int lda, size_t sAz,
    const short* __restrict__ B, int ldb, size_t sBz,
    TOUT* __restrict__ C, int ldc, size_t sCz,
    int K, float scale)
{
  int bx, by;
  if constexpr (MODE == 1) {
    const int i = blockIdx.x;
    by = (int)((__builtin_sqrtf(8.f * (float)i + 1.f) - 1.f) * 0.5f);
    if (((by * (by + 1)) >> 1) > i) by--;
    else if ((((by + 1) * (by + 2)) >> 1) <= i) by++;
    bx = i - ((by * (by + 1)) >> 1);
  } else {
    bx = blockIdx.x; by = blockIdx.y;
  }
  const int z = blockIdx.z;
  const int tri_by = (by * (by + 1)) >> 1;

  A += (size_t)z * sAz;
  B += (size_t)z * sBz;
  C += (size_t)z * sCz;

  const int NT = K >> 5;

  __shared__ short As[3][256 * 32];
  __shared__ short Bs[3][256 * 32];

  const int t = threadIdx.x;
  const int lane = t & 63;
  const int wave = t >> 6;
  const int wm = wave >> 2;
  const int wn = wave & 3;
  const int fr = lane & 15, kh = lane >> 4;
  const int koff = ((kh ^ ((fr >> 1) & 3)) << 3);

  int srow[2], scol[2];
  #pragma unroll
  for (int j = 0; j < 2; j++) {
    int e = j * 512 + t;
    srow[j] = e >> 2;
    scol[j] = (((e & 3) ^ ((e >> 3) & 3)) << 3);
  }

  f32x4 acc[8][4];
  #pragma unroll
  for (int i = 0; i < 8; i++)
    #pragma unroll
    for (int j = 0; j < 4; j++) acc[i][j] = (f32x4){0.f, 0.f, 0.f, 0.f};

  auto STAGE_A = [&](int kt) {
    const int buf = kt % 3, k0 = kt * 32;
    #pragma unroll
    for (int j = 0; j < 2; j++) {
      const short* pa = A + (size_t)(by * 256 + srow[j]) * lda + k0 + scol[j];
      GLDS(pa, (char*)&As[buf][0] + j * 8192 + wave * 1024);
    }
  };
  auto STAGE_B = [&](int kt) {
    const int buf = kt % 3, k0 = kt * 32;
    #pragma unroll
    for (int j = 0; j < 2; j++) {
      const short* pb = B + (size_t)(bx * 256 + srow[j]) * ldb + k0 + scol[j];
      GLDS(pb, (char*)&Bs[buf][0] + j * 8192 + wave * 1024);
    }
  };

  STAGE_A(0); STAGE_B(0);
  STAGE_A(1); STAGE_B(1);
  asm volatile("s_waitcnt vmcnt(4)\ns_barrier" ::: "memory");

  const int arow = wm * 128 + fr;
  const int brow = wn * 64 + fr;

  for (int kt = 0; kt < NT; kt++) {
    const short* as = &As[kt % 3][0];
    const short* bs = &Bs[kt % 3][0];
    short8 af[4], bfr[4];

    #pragma unroll
    for (int n = 0; n < 4; n++) bfr[n] = *(const short8*)&bs[(brow + n * 16) * 32 + koff];
    #pragma unroll
    for (int m = 0; m < 4; m++) af[m] = *(const short8*)&as[(arow + m * 16) * 32 + koff];
    if (kt + 2 < NT) STAGE_A(kt + 2);
    __builtin_amdgcn_s_barrier();
    asm volatile("s_waitcnt lgkmcnt(0)" ::: "memory");
    __builtin_amdgcn_sched_barrier(0);
    __builtin_amdgcn_s_setprio(1);
    #pragma unroll
    for (int m = 0; m < 4; m++)
      #pragma unroll
      for (int n = 0; n < 4; n++)
        acc[m][n] = __builtin_amdgcn_mfma_f32_16x16x32_bf16(af[m], bfr[n], acc[m][n], 0, 0, 0);
    __builtin_amdgcn_s_setprio(0);
    __builtin_amdgcn_sched_barrier(0);

    #pragma unroll
    for (int m = 0; m < 4; m++) af[m] = *(const short8*)&as[(arow + (m + 4) * 16) * 32 + koff];
    if (kt + 2 < NT) STAGE_B(kt + 2);
    __builtin_amdgcn_s_barrier();
    asm volatile("s_waitcnt lgkmcnt(0)" ::: "memory");
    __builtin_amdgcn_sched_barrier(0);
    __builtin_amdgcn_s_setprio(1);
    #pragma unroll
    for (int m = 0; m < 4; m++)
      #pragma unroll
      for (int n = 0; n < 4; n++)
        acc[m + 4][n] = __builtin_amdgcn_mfma_f32_16x16x32_bf16(af[m], bfr[n], acc[m + 4][n], 0, 0, 0);
    __builtin_amdgcn_s_setprio(0);
    __builtin_amdgcn_sched_barrier(0);

    if (kt + 2 < NT)      asm volatile("s_waitcnt vmcnt(4)\ns_barrier" ::: "memory");
    else if (kt + 1 < NT) asm volatile("s_waitcnt vmcnt(0)\ns_barrier" ::: "memory");
  }

  #pragma unroll
  for (int m = 0; m < 8; m++)
    #pragma unroll
    for (int n = 0; n < 4; n++) {
      int col_l = wn * 64 + n * 16 + fr;
      #pragma unroll
      for (int r = 0; r < 4; r++) {
        int row_l = wm * 128 + m * 16 + kh * 4 + r;
        if constexpr (MODE == 1)
          store_out(C, (size_t)(tri_by + bx) * 65536 + (size_t)row_l * 256 + col_l,
                    acc[m][n][r] * scale);
        else
          store_out(C, (size_t)(by * 256 + row_l) * ldc + bx * 256 + col_l,
                    acc[m][n][r] * scale);
      }
    }
}

// ---------------------------------------------------------------------------
// PV split-K: 256x256 tile, r15 MODE-2 loop body, K-range [kt0,kt1) of BK=32
// tiles. Grid 384: w<128 = single block (by 0-7, full K, -> Out);
// w>=128: by 8-15 split in 2 halves: h0 -> Out, h1 -> f32 partial tile
// (Ppart aliases dead Q2, exactly 32 MiB). Greedy scheduler balances the
// 128-block second round onto early-finishing CUs (makespan 16 -> ~9 units).
// ---------------------------------------------------------------------------
__global__ __launch_bounds__(512, 2) void gemm_pv_split(
    const short* __restrict__ SP, const short* __restrict__ Vt,
    float* __restrict__ Out, float* __restrict__ Ppart)
{
  const int w = blockIdx.x;
  int by, bx, z, kt0, kt1, u;
  bool topart;
  if (w < 128) {
    by = w & 7; bx = (w >> 3) & 3; z = w >> 5;
    kt0 = 0; kt1 = (by + 1) * 8; topart = false; u = 0;
  } else {
    const int v = w - 128;
    const int h = v & 1;
    u = v >> 1;                       // [0,128)
    by = 8 + (u & 7); bx = (u >> 3) & 3; z = u >> 5;
    const int n = (by + 1) * 8, half = n >> 1;
    kt0 = h ? half : 0;
    kt1 = h ? n : half;
    topart = (h == 1);
  }
  const int tri_by = (by * (by + 1)) >> 1;
  const short* A = SP + (size_t)z * 136 * 65536;

  __shared__ short As[3][256 * 32];
  __shared__ short Bs[3][256 * 32];

  const int t = threadIdx.x;
  const int lane = t & 63;
  const int wave = t >> 6;
  const int wm = wave >> 2;
  const int wn = wave & 3;
  const int fr = lane & 15, kh = lane >> 4;
  const int koff = ((kh ^ ((fr >> 1) & 3)) << 3);

  int srow[2], scol[2];
  #pragma unroll
  for (int j = 0; j < 2; j++) {
    int e = j * 512 + t;
    srow[j] = e >> 2;
    scol[j] = (((e & 3) ^ ((e >> 3) & 3)) << 3);
  }

  f32x4 acc[8][4];
  #pragma unroll
  for (int i = 0; i < 8; i++)
    #pragma unroll
    for (int j = 0; j < 4; j++) acc[i][j] = (f32x4){0.f, 0.f, 0.f, 0.f};

  auto STAGE_A = [&](int kt) {
    const int buf = kt % 3, k0 = kt * 32;
    #pragma unroll
    for (int j = 0; j < 2; j++) {
      const short* pa = A + (size_t)(tri_by + (k0 >> 8)) * 65536
                          + (size_t)srow[j] * 256 + (k0 & 255) + scol[j];
      GLDS(pa, (char*)&As[buf][0] + j * 8192 + wave * 1024);
    }
  };
  auto STAGE_B = [&](int kt) {
    const int buf = kt % 3, k0 = kt * 32;
    #pragma unroll
    for (int j = 0; j < 2; j++) {
      const short* pb = Vt + (size_t)(bx * 256 + srow[j]) * 16384 + z * 4096 + k0 + scol[j];
      GLDS(pb, (char*)&Bs[buf][0] + j * 8192 + wave * 1024);
    }
  };

  STAGE_A(kt0); STAGE_B(kt0);
  STAGE_A(kt0 + 1); STAGE_B(kt0 + 1);
  asm volatile("s_waitcnt vmcnt(4)\ns_barrier" ::: "memory");

  const int arow = wm * 128 + fr;
  const int brow = wn * 64 + fr;

  for (int kt = kt0; kt < kt1; kt++) {
    const short* as = &As[kt % 3][0];
    const short* bs = &Bs[kt % 3][0];
    short8 af[4], bfr[4];

    #pragma unroll
    for (int n = 0; n < 4; n++) bfr[n] = *(const short8*)&bs[(brow + n * 16) * 32 + koff];
    #pragma unroll
    for (int m = 0; m < 4; m++) af[m] = *(const short8*)&as[(arow + m * 16) * 32 + koff];
    if (kt + 2 < kt1) STAGE_A(kt + 2);
    __builtin_amdgcn_s_barrier();
    asm volatile("s_waitcnt lgkmcnt(0)" ::: "memory");
    __builtin_amdgcn_sched_barrier(0);
    __builtin_amdgcn_s_setprio(1);
    #pragma unroll
    for (int m = 0; m < 4; m++)
      #pragma unroll
      for (int n = 0; n < 4; n++)
        acc[m][n] = __builtin_amdgcn_mfma_f32_16x16x32_bf16(af[m], bfr[n], acc[m][n], 0, 0, 0);
    __builtin_amdgcn_s_setprio(0);
    __builtin_amdgcn_sched_barrier(0);

    #pragma unroll
    for (int m = 0; m < 4; m++) af[m] = *(const short8*)&as[(arow + (m + 4) * 16) * 32 + koff];
    if (kt + 2 < kt1) STAGE_B(kt + 2);
    __builtin_amdgcn_s_barrier();
    asm volatile("s_waitcnt lgkmcnt(0)" ::: "memory");
    __builtin_amdgcn_sched_barrier(0);
    __builtin_amdgcn_s_setprio(1);
    #pragma unroll
    for (int m = 0; m < 4; m++)
      #pragma unroll
      for (int n = 0; n < 4; n++)
        acc[m + 4][n] = __builtin_amdgcn_mfma_f32_16x16x32_bf16(af[m], bfr[n], acc[m + 4][n], 0, 0, 0);
    __builtin_amdgcn_s_setprio(0);
    __builtin_amdgcn_sched_barrier(0);

    if (kt + 2 < kt1)      asm volatile("s_waitcnt vmcnt(4)\ns_barrier" ::: "memory");
    else if (kt + 1 < kt1) asm volatile("s_waitcnt vmcnt(0)\ns_barrier" ::: "memory");
  }

  #pragma unroll
  for (int m = 0; m < 8; m++)
    #pragma unroll
    for (int n = 0; n < 4; n++) {
      int col_l = wn * 64 + n * 16 + fr;
      #pragma unroll
      for (int r = 0; r < 4; r++) {
        int row_l = wm * 128 + m * 16 + kh * 4 + r;
        if (topart)
          Ppart[(size_t)u * 65536 + (size_t)row_l * 256 + col_l] = acc[m][n][r];
        else
          Out[(size_t)z * 4096 * 1024 + (size_t)(by * 256 + row_l) * 1024
              + bx * 256 + col_l] = acc[m][n][r];
      }
    }
}

// Out += Ppart for the 128 split tiles. Grid (128, 8): 32 rows x 256 cols each.
__global__ __launch_bounds__(256) void pv_reduce(
    const float* __restrict__ Ppart, float* __restrict__ Out)
{
  const int u = blockIdx.x;
  const int rg = blockIdx.y;
  const int by = 8 + (u & 7), bx = (u >> 3) & 3, z = u >> 5;
  const int t = threadIdx.x;
  const float* src = Ppart + (size_t)u * 65536 + (size_t)rg * 32 * 256;
  float* dst = Out + (size_t)z * 4096 * 1024
                   + (size_t)(by * 256 + rg * 32) * 1024 + bx * 256;
  for (int i = t * 4; i < 8192; i += 1024) {
    int row = i >> 8, col = i & 255;
    f32x4 a = *(const f32x4*)&src[i];
    float* d = &dst[(size_t)row * 1024 + col];
    f32x4 b = *(const f32x4*)d;
    b[0] += a[0]; b[1] += a[1]; b[2] += a[2]; b[3] += a[3];
    *(f32x4*)d = b;
  }
}

// ---------------------------------------------------------------------------
// Small 128x128 GEMM (round-3 proven loop) — only for W2T = Wk^T.Wq (8x8).
// ---------------------------------------------------------------------------
__global__ __launch_bounds__(256) void gemm128(
    const short* __restrict__ A, int lda,
    const short* __restrict__ B, int ldb,
    bf16* __restrict__ C, int ldc, int K, float scale)
{
  const int bx = blockIdx.x, by = blockIdx.y;
  __shared__ short a_lds[128 * 32];
  __shared__ short b_lds[128 * 32];

  const int t = threadIdx.x;
  const int lane = t & 63;
  const int wave = t >> 6;
  const int wm = wave >> 1, wn = wave & 1;
  const int fr = lane & 15, kh = lane >> 4;

  f32x4 acc[4][4];
  #pragma unroll
  for (int i = 0; i < 4; i++)
    #pragma unroll
    for (int j = 0; j < 4; j++) acc[i][j] = (f32x4){0.f, 0.f, 0.f, 0.f};

  for (int k0 = 0; k0 < K; k0 += 32) {
    #pragma unroll
    for (int i = 0; i < 2; i++) {
      int e = i * 256 + t;
      int r_ = e >> 2, c_ = (e & 3) * 8;
      GLDS(A + (size_t)(by * 128 + r_) * lda + k0 + c_, (char*)a_lds + i * 4096 + wave * 1024);
      GLDS(B + (size_t)(bx * 128 + r_) * ldb + k0 + c_, (char*)b_lds + i * 4096 + wave * 1024);
    }
    __syncthreads();

    short8 af[4], bfr[4];
    #pragma unroll
    for (int m = 0; m < 4; m++)
      af[m] = *(const short8*)&a_lds[(wm * 64 + m * 16 + fr) * 32 + kh * 8];
    #pragma unroll
    for (int n = 0; n < 4; n++)
      bfr[n] = *(const short8*)&b_lds[(wn * 64 + n * 16 + fr) * 32 + kh * 8];
    #pragma unroll
    for (int m = 0; m < 4; m++)
      #pragma unroll
      for (int n = 0; n < 4; n++)
        acc[m][n] = __builtin_amdgcn_mfma_f32_16x16x32_bf16(af[m], bfr[n], acc[m][n], 0, 0, 0);
    __syncthreads();
  }

  #pragma unroll
  for (int m = 0; m < 4; m++)
    #pragma unroll
    for (int n = 0; n < 4; n++) {
      int col = bx * 128 + wn * 64 + n * 16 + fr;
      #pragma unroll
      for (int r = 0; r < 4; r++) {
        int row = by * 128 + wm * 64 + m * 16 + kh * 4 + r;
        C[(size_t)row * ldc + col] = __float2bfloat16(acc[m][n][r] * scale);
      }
    }
}

// fp32 -> bf16 elementwise convert with scale
__global__ __launch_bounds__(256) void cvt_bf16(
    const float* __restrict__ in, bf16* __restrict__ out, int n, float scale)
{
  for (int i = (blockIdx.x * 256 + threadIdx.x) * 8; i < n; i += gridDim.x * 2048) {
    f32x4 v0 = *(const f32x4*)&in[i];
    f32x4 v1 = *(const f32x4*)&in[i + 4];
    short8 o = { f2bfbits(v0[0] * scale), f2bfbits(v0[1] * scale),
                 f2bfbits(v0[2] * scale), f2bfbits(v0[3] * scale),
                 f2bfbits(v1[0] * scale), f2bfbits(v1[1] * scale),
                 f2bfbits(v1[2] * scale), f2bfbits(v1[3] * scale) };
    *(short8*)&out[i] = o;
  }
}

// fp32 (N x N) -> bf16 transposed (N x N): out[c][r] = in[r][c]. 64x64 tiles.
__global__ __launch_bounds__(256) void cvt_t_bf16(
    const float* __restrict__ in, bf16* __restrict__ out, int N)
{
  __shared__ float tile[64][65];
  const int bx = blockIdx.x, by = blockIdx.y;
  const int t = threadIdx.x;
  #pragma unroll
  for (int i = 0; i < 16; i++) {
    int e = i * 256 + t;
    int r = e >> 6, c = e & 63;
    tile[r][c] = in[(size_t)(by * 64 + r) * N + bx * 64 + c];
  }
  __syncthreads();
  #pragma unroll
  for (int i = 0; i < 16; i++) {
    int e = i * 256 + t;
    int r = e >> 6, c = e & 63;
    out[(size_t)(bx * 64 + r) * N + by * 64 + c] = __float2bfloat16(tile[c][r]);
  }
}

// In-place softmax on 256-packed block-triangular bf16 scores.
__global__ __launch_bounds__(256) void softmax_causal_packed(short* SP, int T)
{
  __shared__ float rowv[4096];
  __shared__ float red[4];
  const int r = blockIdx.x;
  const int z = blockIdx.y;
  const int rb = r >> 8, rl = r & 255;
  const size_t tri = (size_t)((rb * (rb + 1)) >> 1);
  short* base = SP + (size_t)z * 136 * 65536;
  const int L = r + 1;
  const int kend = (rb + 1) * 256;
  const int t = threadIdx.x;

  float lmax = -3.0e38f;
  for (int i = t * 8; i < kend; i += 2048) {
    short8 s = *(const short8*)(base + (tri + (i >> 8)) * 65536 + (size_t)rl * 256 + (i & 255));
    #pragma unroll
    for (int j = 0; j < 8; j++) {
      float v = bf2f(s[j]);
      rowv[i + j] = v;
      if (i + j < L) lmax = fmaxf(lmax, v);
    }
  }
  #pragma unroll
  for (int o = 32; o > 0; o >>= 1) lmax = fmaxf(lmax, __shfl_down(lmax, o));
  if ((t & 63) == 0) red[t >> 6] = lmax;
  __syncthreads();
  const float m = fmaxf(fmaxf(red[0], red[1]), fmaxf(red[2], red[3]));
  __syncthreads();

  float lsum = 0.f;
  for (int i = t; i < kend; i += 256) {
    float e = (i < L) ? __expf(rowv[i] - m) : 0.f;
    rowv[i] = e;
    lsum += e;
  }
  #pragma unroll
  for (int o = 32; o > 0; o >>= 1) lsum += __shfl_down(lsum, o);
  if ((t & 63) == 0) red[t >> 6] = lsum;
  __syncthreads();
  const float inv = 1.f / (red[0] + red[1] + red[2] + red[3]);

  for (int i = t * 8; i < kend; i += 2048) {
    short8 o;
    #pragma unroll
    for (int j = 0; j < 8; j++) o[j] = f2bfbits(rowv[i + j] * inv);
    *(short8*)(base + (tri + (i >> 8)) * 65536 + (size_t)rl * 256 + (i & 255)) = o;
  }
}

extern "C" void kernel_launch(void* const* d_in, const int* in_sizes, int n_in,
                              void* d_out, int out_size, void* d_ws, size_t ws_size,
                              hipStream_t stream) {
  (void)in_sizes; (void)n_in; (void)out_size; (void)ws_size;
  const float* X  = (const float*)d_in[0];   // (B,T,E)
  const float* Wq = (const float*)d_in[1];   // (A,E)
  const float* Wk = (const float*)d_in[2];
  const float* Wv = (const float*)d_in[3];
  float* Out = (float*)d_out;                // (B,T,A) fp32

  const int Bn = 4, T = 4096, E = 1024, Ad = 1024;
  const int M = Bn * T;  // 16384

  // Algebra: S = X.(Wq^T Wk / 32).X^T  — K-projection eliminated
  char* ws = (char*)d_ws;
  short* Q2  = (short*)ws;                    // [0,32Mi)   M x 1024 (dead after S)
  short* Vt  = (short*)(ws + 33554432);       // [32,64Mi)  Ad x M
  short* Xb  = (short*)(ws + 67108864);       // [64,96Mi)  M x E
  short* WqT = (short*)(ws + 100663296);      // E x A
  short* WkT = (short*)(ws + 102760448);
  short* Wvb = (short*)(ws + 104857600);
  short* W2T = (short*)(ws + 106954752);
  short* SP  = (short*)(ws + 109051904);      // 4 x 136 x 256x256 bf16
  float* Ppart = (float*)ws;                  // aliases dead Q2: 128 x 64K f32 = 32 MiB

  dim3 blk(256), blk5(512);
  const size_t SPz = (size_t)136 * 65536;

  // conversions
  cvt_bf16<<<dim3(8192), blk, 0, stream>>>(X, (bf16*)Xb, M * E, 1.0f);
  cvt_t_bf16<<<dim3(16, 16), blk, 0, stream>>>(Wq, (bf16*)WqT, E);
  cvt_t_bf16<<<dim3(16, 16), blk, 0, stream>>>(Wk, (bf16*)WkT, E);
  cvt_bf16<<<dim3(512), blk, 0, stream>>>(Wv, (bf16*)Wvb, Ad * E, 1.0f);

  // W2T[e2][e1] = sum_a Wk[a][e2]*Wq[a][e1] / 32
  gemm128<<<dim3(8, 8), blk, 0, stream>>>(
      WkT, Ad, WqT, Ad, (bf16*)W2T, E, Ad, 0.03125f);

  // Q2 (M x 1024) = Xb . W2T^T
  gemm256<bf16, 0><<<dim3(1024 / 256, M / 256), blk5, 0, stream>>>(
      Xb, E, 0, W2T, E, 0, (bf16*)Q2, 1024, 0, E, 1.0f);

  // all-batch V^T: Vt (Ad x M) = Wvb . Xb^T
  gemm256<bf16, 0><<<dim3(M / 256, Ad / 256), blk5, 0, stream>>>(
      Wvb, E, 0, Xb, E, 0, (bf16*)Vt, M, 0, E, 1.0f);

  // S (256-packed tri, all batches) = Q2 . Xb^T
  gemm256<bf16, 1><<<dim3(136, 1, Bn), blk5, 0, stream>>>(
      Q2, 1024, (size_t)T * 1024,
      Xb, 1024, (size_t)T * 1024,
      (bf16*)SP, 256, SPz, E, 1.0f);

  // in-place softmax on packed scores (all batches)
  softmax_causal_packed<<<dim3(T, Bn), blk, 0, stream>>>(SP, T);

  // O = P.V — split-K: by 0-7 single, by 8-15 halved (h1 -> Ppart), grid 384
  gemm_pv_split<<<dim3(384), blk5, 0, stream>>>(SP, Vt, Out, Ppart);
  // Out += Ppart for the 128 split tiles
  pv_reduce<<<dim3(128, 8), blk, 0, stream>>>(Ppart, Out);
}

// Round 21
// 382.097 us; speedup vs baseline: 1.0664x; 1.0664x over previous
//
#include <hip/hip_runtime.h>
#include <hip/hip_bf16.h>

using bf16 = __hip_bfloat16;

typedef __attribute__((ext_vector_type(4))) float f32x4;
typedef __attribute__((ext_vector_type(8))) short short8;

typedef const void __attribute__((address_space(1)))* gas1_t;
typedef void __attribute__((address_space(3)))* las3_t;
#define GLDS(gp, lp) __builtin_amdgcn_global_load_lds((gas1_t)(gp), (las3_t)(lp), 16, 0, 0)

__device__ inline short f2bfbits(float f) {
  union { bf16 h; short s; } u;
  u.h = __float2bfloat16(f);
  return u.s;
}
__device__ inline float bf2f(short u) {
  unsigned x = ((unsigned)(unsigned short)u) << 16;
  float f; __builtin_memcpy(&f, &x, 4); return f;
}

__device__ inline void store_out(float* C, size_t idx, float v) { C[idx] = v; }
__device__ inline void store_out(bf16* C, size_t idx, float v) { C[idx] = __float2bfloat16(v); }

// ---------------------------------------------------------------------------
// ROUND-15 gemm256 (empirical optimum, 384us total): 256x256, BK=32, 8 waves
// (2M x 4N), 3-ring LDS + counted vmcnt(4), chunk-XOR swizzle both-sides.
// MODE 0: plain, identity raster.
// MODE 1: causal S -> tri grid, C to 256-packed tri bf16.
// MODE 2: PV -> A is 256-packed P, K limited to (by+1)*256.
// Session notes: all schedule variants (2-buf, 8-phase, split-K, balanced
// pairing) measured 580-640 TF — this structure is at the floor; the W2
// algebra trick (-34 GF) was the main win. Flash fusion infeasible at D=1024.
// ---------------------------------------------------------------------------
template<typename TOUT, int MODE>
__global__ __launch_bounds__(512, 2) void gemm256(
    const short* __restrict__ A, int lda, size_t sAz,
    const short* __restrict__ B, int ldb, size_t sBz,
    TOUT* __restrict__ C, int ldc, size_t sCz,
    int K, float scale)
{
  int bx, by;
  if constexpr (MODE == 1) {
    const int i = blockIdx.x;
    by = (int)((__builtin_sqrtf(8.f * (float)i + 1.f) - 1.f) * 0.5f);
    if (((by * (by + 1)) >> 1) > i) by--;
    else if ((((by + 1) * (by + 2)) >> 1) <= i) by++;
    bx = i - ((by * (by + 1)) >> 1);
  } else {
    bx = blockIdx.x; by = blockIdx.y;
  }
  const int z = blockIdx.z;
  const int tri_by = (by * (by + 1)) >> 1;

  A += (size_t)z * sAz;
  B += (size_t)z * sBz;
  C += (size_t)z * sCz;

  int Klen = K;
  if (MODE == 2) Klen = min(K, (by + 1) * 256);
  const int NT = Klen >> 5;

  __shared__ short As[3][256 * 32];
  __shared__ short Bs[3][256 * 32];

  const int t = threadIdx.x;
  const int lane = t & 63;
  const int wave = t >> 6;
  const int wm = wave >> 2;
  const int wn = wave & 3;
  const int fr = lane & 15, kh = lane >> 4;
  const int koff = ((kh ^ ((fr >> 1) & 3)) << 3);

  int srow[2], scol[2];
  #pragma unroll
  for (int j = 0; j < 2; j++) {
    int e = j * 512 + t;
    srow[j] = e >> 2;
    scol[j] = (((e & 3) ^ ((e >> 3) & 3)) << 3);
  }

  f32x4 acc[8][4];
  #pragma unroll
  for (int i = 0; i < 8; i++)
    #pragma unroll
    for (int j = 0; j < 4; j++) acc[i][j] = (f32x4){0.f, 0.f, 0.f, 0.f};

  auto STAGE_A = [&](int kt) {
    const int buf = kt % 3, k0 = kt * 32;
    #pragma unroll
    for (int j = 0; j < 2; j++) {
      const short* pa;
      if constexpr (MODE == 2)
        pa = A + (size_t)(tri_by + (k0 >> 8)) * 65536 + (size_t)srow[j] * 256 + (k0 & 255) + scol[j];
      else
        pa = A + (size_t)(by * 256 + srow[j]) * lda + k0 + scol[j];
      GLDS(pa, (char*)&As[buf][0] + j * 8192 + wave * 1024);
    }
  };
  auto STAGE_B = [&](int kt) {
    const int buf = kt % 3, k0 = kt * 32;
    #pragma unroll
    for (int j = 0; j < 2; j++) {
      const short* pb = B + (size_t)(bx * 256 + srow[j]) * ldb + k0 + scol[j];
      GLDS(pb, (char*)&Bs[buf][0] + j * 8192 + wave * 1024);
    }
  };

  STAGE_A(0); STAGE_B(0);
  STAGE_A(1); STAGE_B(1);
  asm volatile("s_waitcnt vmcnt(4)\ns_barrier" ::: "memory");

  const int arow = wm * 128 + fr;
  const int brow = wn * 64 + fr;

  for (int kt = 0; kt < NT; kt++) {
    const short* as = &As[kt % 3][0];
    const short* bs = &Bs[kt % 3][0];
    short8 af[4], bfr[4];

    #pragma unroll
    for (int n = 0; n < 4; n++) bfr[n] = *(const short8*)&bs[(brow + n * 16) * 32 + koff];
    #pragma unroll
    for (int m = 0; m < 4; m++) af[m] = *(const short8*)&as[(arow + m * 16) * 32 + koff];
    if (kt + 2 < NT) STAGE_A(kt + 2);
    __builtin_amdgcn_s_barrier();
    asm volatile("s_waitcnt lgkmcnt(0)" ::: "memory");
    __builtin_amdgcn_sched_barrier(0);
    __builtin_amdgcn_s_setprio(1);
    #pragma unroll
    for (int m = 0; m < 4; m++)
      #pragma unroll
      for (int n = 0; n < 4; n++)
        acc[m][n] = __builtin_amdgcn_mfma_f32_16x16x32_bf16(af[m], bfr[n], acc[m][n], 0, 0, 0);
    __builtin_amdgcn_s_setprio(0);
    __builtin_amdgcn_sched_barrier(0);

    #pragma unroll
    for (int m = 0; m < 4; m++) af[m] = *(const short8*)&as[(arow + (m + 4) * 16) * 32 + koff];
    if (kt + 2 < NT) STAGE_B(kt + 2);
    __builtin_amdgcn_s_barrier();
    asm volatile("s_waitcnt lgkmcnt(0)" ::: "memory");
    __builtin_amdgcn_sched_barrier(0);
    __builtin_amdgcn_s_setprio(1);
    #pragma unroll
    for (int m = 0; m < 4; m++)
      #pragma unroll
      for (int n = 0; n < 4; n++)
        acc[m + 4][n] = __builtin_amdgcn_mfma_f32_16x16x32_bf16(af[m], bfr[n], acc[m + 4][n], 0, 0, 0);
    __builtin_amdgcn_s_setprio(0);
    __builtin_amdgcn_sched_barrier(0);

    if (kt + 2 < NT)      asm volatile("s_waitcnt vmcnt(4)\ns_barrier" ::: "memory");
    else if (kt + 1 < NT) asm volatile("s_waitcnt vmcnt(0)\ns_barrier" ::: "memory");
  }

  #pragma unroll
  for (int m = 0; m < 8; m++)
    #pragma unroll
    for (int n = 0; n < 4; n++) {
      int col_l = wn * 64 + n * 16 + fr;
      #pragma unroll
      for (int r = 0; r < 4; r++) {
        int row_l = wm * 128 + m * 16 + kh * 4 + r;
        if constexpr (MODE == 1)
          store_out(C, (size_t)(tri_by + bx) * 65536 + (size_t)row_l * 256 + col_l,
                    acc[m][n][r] * scale);
        else
          store_out(C, (size_t)(by * 256 + row_l) * ldc + bx * 256 + col_l,
                    acc[m][n][r] * scale);
      }
    }
}

// ---------------------------------------------------------------------------
// Small 128x128 GEMM (round-3 proven loop) — only for W2T = Wk^T.Wq (8x8).
// ---------------------------------------------------------------------------
__global__ __launch_bounds__(256) void gemm128(
    const short* __restrict__ A, int lda,
    const short* __restrict__ B, int ldb,
    bf16* __restrict__ C, int ldc, int K, float scale)
{
  const int bx = blockIdx.x, by = blockIdx.y;
  __shared__ short a_lds[128 * 32];
  __shared__ short b_lds[128 * 32];

  const int t = threadIdx.x;
  const int lane = t & 63;
  const int wave = t >> 6;
  const int wm = wave >> 1, wn = wave & 1;
  const int fr = lane & 15, kh = lane >> 4;

  f32x4 acc[4][4];
  #pragma unroll
  for (int i = 0; i < 4; i++)
    #pragma unroll
    for (int j = 0; j < 4; j++) acc[i][j] = (f32x4){0.f, 0.f, 0.f, 0.f};

  for (int k0 = 0; k0 < K; k0 += 32) {
    #pragma unroll
    for (int i = 0; i < 2; i++) {
      int e = i * 256 + t;
      int r_ = e >> 2, c_ = (e & 3) * 8;
      GLDS(A + (size_t)(by * 128 + r_) * lda + k0 + c_, (char*)a_lds + i * 4096 + wave * 1024);
      GLDS(B + (size_t)(bx * 128 + r_) * ldb + k0 + c_, (char*)b_lds + i * 4096 + wave * 1024);
    }
    __syncthreads();

    short8 af[4], bfr[4];
    #pragma unroll
    for (int m = 0; m < 4; m++)
      af[m] = *(const short8*)&a_lds[(wm * 64 + m * 16 + fr) * 32 + kh * 8];
    #pragma unroll
    for (int n = 0; n < 4; n++)
      bfr[n] = *(const short8*)&b_lds[(wn * 64 + n * 16 + fr) * 32 + kh * 8];
    #pragma unroll
    for (int m = 0; m < 4; m++)
      #pragma unroll
      for (int n = 0; n < 4; n++)
        acc[m][n] = __builtin_amdgcn_mfma_f32_16x16x32_bf16(af[m], bfr[n], acc[m][n], 0, 0, 0);
    __syncthreads();
  }

  #pragma unroll
  for (int m = 0; m < 4; m++)
    #pragma unroll
    for (int n = 0; n < 4; n++) {
      int col = bx * 128 + wn * 64 + n * 16 + fr;
      #pragma unroll
      for (int r = 0; r < 4; r++) {
        int row = by * 128 + wm * 64 + m * 16 + kh * 4 + r;
        C[(size_t)row * ldc + col] = __float2bfloat16(acc[m][n][r] * scale);
      }
    }
}

// fp32 -> bf16 elementwise convert with scale
__global__ __launch_bounds__(256) void cvt_bf16(
    const float* __restrict__ in, bf16* __restrict__ out, int n, float scale)
{
  for (int i = (blockIdx.x * 256 + threadIdx.x) * 8; i < n; i += gridDim.x * 2048) {
    f32x4 v0 = *(const f32x4*)&in[i];
    f32x4 v1 = *(const f32x4*)&in[i + 4];
    short8 o = { f2bfbits(v0[0] * scale), f2bfbits(v0[1] * scale),
                 f2bfbits(v0[2] * scale), f2bfbits(v0[3] * scale),
                 f2bfbits(v1[0] * scale), f2bfbits(v1[1] * scale),
                 f2bfbits(v1[2] * scale), f2bfbits(v1[3] * scale) };
    *(short8*)&out[i] = o;
  }
}

// fp32 (N x N) -> bf16 transposed (N x N): out[c][r] = in[r][c]. 64x64 tiles.
__global__ __launch_bounds__(256) void cvt_t_bf16(
    const float* __restrict__ in, bf16* __restrict__ out, int N)
{
  __shared__ float tile[64][65];
  const int bx = blockIdx.x, by = blockIdx.y;
  const int t = threadIdx.x;
  #pragma unroll
  for (int i = 0; i < 16; i++) {
    int e = i * 256 + t;
    int r = e >> 6, c = e & 63;
    tile[r][c] = in[(size_t)(by * 64 + r) * N + bx * 64 + c];
  }
  __syncthreads();
  #pragma unroll
  for (int i = 0; i < 16; i++) {
    int e = i * 256 + t;
    int r = e >> 6, c = e & 63;
    out[(size_t)(bx * 64 + r) * N + by * 64 + c] = __float2bfloat16(tile[c][r]);
  }
}

// In-place softmax on 256-packed block-triangular bf16 scores.
// Vectorized exp/sum pass (f32x4) — only remaining scalar loop removed.
__global__ __launch_bounds__(256) void softmax_causal_packed(short* SP, int T)
{
  __shared__ float rowv[4096];
  __shared__ float red[4];
  const int r = blockIdx.x;
  const int z = blockIdx.y;
  const int rb = r >> 8, rl = r & 255;
  const size_t tri = (size_t)((rb * (rb + 1)) >> 1);
  short* base = SP + (size_t)z * 136 * 65536;
  const int L = r + 1;
  const int kend = (rb + 1) * 256;
  const int t = threadIdx.x;

  float lmax = -3.0e38f;
  for (int i = t * 8; i < kend; i += 2048) {
    short8 s = *(const short8*)(base + (tri + (i >> 8)) * 65536 + (size_t)rl * 256 + (i & 255));
    #pragma unroll
    for (int j = 0; j < 8; j++) {
      float v = bf2f(s[j]);
      rowv[i + j] = v;
      if (i + j < L) lmax = fmaxf(lmax, v);
    }
  }
  #pragma unroll
  for (int o = 32; o > 0; o >>= 1) lmax = fmaxf(lmax, __shfl_down(lmax, o));
  if ((t & 63) == 0) red[t >> 6] = lmax;
  __syncthreads();
  const float m = fmaxf(fmaxf(red[0], red[1]), fmaxf(red[2], red[3]));
  __syncthreads();

  float lsum = 0.f;
  for (int i = t * 4; i < kend; i += 1024) {
    f32x4 v = *(const f32x4*)&rowv[i];
    f32x4 e;
    #pragma unroll
    for (int j = 0; j < 4; j++)
      e[j] = (i + j < L) ? __expf(v[j] - m) : 0.f;
    *(f32x4*)&rowv[i] = e;
    lsum += e[0] + e[1] + e[2] + e[3];
  }
  #pragma unroll
  for (int o = 32; o > 0; o >>= 1) lsum += __shfl_down(lsum, o);
  if ((t & 63) == 0) red[t >> 6] = lsum;
  __syncthreads();
  const float inv = 1.f / (red[0] + red[1] + red[2] + red[3]);

  for (int i = t * 8; i < kend; i += 2048) {
    short8 o;
    #pragma unroll
    for (int j = 0; j < 8; j++) o[j] = f2bfbits(rowv[i + j] * inv);
    *(short8*)(base + (tri + (i >> 8)) * 65536 + (size_t)rl * 256 + (i & 255)) = o;
  }
}

extern "C" void kernel_launch(void* const* d_in, const int* in_sizes, int n_in,
                              void* d_out, int out_size, void* d_ws, size_t ws_size,
                              hipStream_t stream) {
  (void)in_sizes; (void)n_in; (void)out_size; (void)ws_size;
  const float* X  = (const float*)d_in[0];   // (B,T,E)
  const float* Wq = (const float*)d_in[1];   // (A,E)
  const float* Wk = (const float*)d_in[2];
  const float* Wv = (const float*)d_in[3];
  float* Out = (float*)d_out;                // (B,T,A) fp32

  const int Bn = 4, T = 4096, E = 1024, Ad = 1024;
  const int M = Bn * T;  // 16384

  // Algebra: S = X.(Wq^T Wk / 32).X^T  — K-projection eliminated
  char* ws = (char*)d_ws;
  short* Q2  = (short*)ws;                    // [0,32Mi)   M x 1024
  short* Vt  = (short*)(ws + 33554432);       // [32,64Mi)  Ad x M
  short* Xb  = (short*)(ws + 67108864);       // [64,96Mi)  M x E
  short* WqT = (short*)(ws + 100663296);      // E x A
  short* WkT = (short*)(ws + 102760448);
  short* Wvb = (short*)(ws + 104857600);
  short* W2T = (short*)(ws + 106954752);
  short* SP  = (short*)(ws + 109051904);      // 4 x 136 x 256x256 bf16

  dim3 blk(256), blk5(512);
  const size_t SPz = (size_t)136 * 65536;

  // conversions
  cvt_bf16<<<dim3(8192), blk, 0, stream>>>(X, (bf16*)Xb, M * E, 1.0f);
  cvt_t_bf16<<<dim3(16, 16), blk, 0, stream>>>(Wq, (bf16*)WqT, E);
  cvt_t_bf16<<<dim3(16, 16), blk, 0, stream>>>(Wk, (bf16*)WkT, E);
  cvt_bf16<<<dim3(512), blk, 0, stream>>>(Wv, (bf16*)Wvb, Ad * E, 1.0f);

  // W2T[e2][e1] = sum_a Wk[a][e2]*Wq[a][e1] / 32
  gemm128<<<dim3(8, 8), blk, 0, stream>>>(
      WkT, Ad, WqT, Ad, (bf16*)W2T, E, Ad, 0.03125f);

  // Q2 (M x 1024) = Xb . W2T^T
  gemm256<bf16, 0><<<dim3(1024 / 256, M / 256), blk5, 0, stream>>>(
      Xb, E, 0, W2T, E, 0, (bf16*)Q2, 1024, 0, E, 1.0f);

  // all-batch V^T: Vt (Ad x M) = Wvb . Xb^T
  gemm256<bf16, 0><<<dim3(M / 256, Ad / 256), blk5, 0, stream>>>(
      Wvb, E, 0, Xb, E, 0, (bf16*)Vt, M, 0, E, 1.0f);

  // S (256-packed tri, all batches) = Q2 . Xb^T
  gemm256<bf16, 1><<<dim3(136, 1, Bn), blk5, 0, stream>>>(
      Q2, 1024, (size_t)T * 1024,
      Xb, 1024, (size_t)T * 1024,
      (bf16*)SP, 256, SPz, E, 1.0f);

  // in-place softmax on packed scores (all batches)
  softmax_causal_packed<<<dim3(T, Bn), blk, 0, stream>>>(SP, T);

  // O = P.V (256-packed P; causal K-limit)
  gemm256<float, 2><<<dim3(Ad / 256, T / 256, Bn), blk5, 0, stream>>>(
      SP, 256, SPz,
      Vt, M, (size_t)T,
      Out, Ad, (size_t)T * Ad, T, 1.0f);
}

// Round 22
// 367.100 us; speedup vs baseline: 1.1100x; 1.0409x over previous
//
#include <hip/hip_runtime.h>
#include <hip/hip_bf16.h>

using bf16 = __hip_bfloat16;

typedef __attribute__((ext_vector_type(4))) float f32x4;
typedef __attribute__((ext_vector_type(8))) short short8;

typedef const void __attribute__((address_space(1)))* gas1_t;
typedef void __attribute__((address_space(3)))* las3_t;
#define GLDS(gp, lp) __builtin_amdgcn_global_load_lds((gas1_t)(gp), (las3_t)(lp), 16, 0, 0)

__device__ inline short f2bfbits(float f) {
  union { bf16 h; short s; } u;
  u.h = __float2bfloat16(f);
  return u.s;
}
__device__ inline float bf2f(short u) {
  unsigned x = ((unsigned)(unsigned short)u) << 16;
  float f; __builtin_memcpy(&f, &x, 4); return f;
}

__device__ inline void store_out(float* C, size_t idx, float v) { C[idx] = v; }
__device__ inline void store_out(bf16* C, size_t idx, float v) { C[idx] = __float2bfloat16(v); }

// ---------------------------------------------------------------------------
// ROUND-15 gemm256 (proven): 256x256, BK=32, 8 waves (2M x 4N), 3-ring LDS +
// counted vmcnt(4), chunk-XOR swizzle. MODE 0: plain; MODE 1: causal S ->
// tri grid, 256-packed tri bf16 out.
// ---------------------------------------------------------------------------
template<typename TOUT, int MODE>
__global__ __launch_bounds__(512, 2) void gemm256(
    const short* __restrict__ A, int lda, size_t sAz,
    const short* __restrict__ B, int ldb, size_t sBz,
    TOUT* __restrict__ C, int ldc, size_t sCz,
    int K, float scale)
{
  int bx, by;
  if constexpr (MODE == 1) {
    const int i = blockIdx.x;
    by = (int)((__builtin_sqrtf(8.f * (float)i + 1.f) - 1.f) * 0.5f);
    if (((by * (by + 1)) >> 1) > i) by--;
    else if ((((by + 1) * (by + 2)) >> 1) <= i) by++;
    bx = i - ((by * (by + 1)) >> 1);
  } else {
    bx = blockIdx.x; by = blockIdx.y;
  }
  const int z = blockIdx.z;
  const int tri_by = (by * (by + 1)) >> 1;

  A += (size_t)z * sAz;
  B += (size_t)z * sBz;
  C += (size_t)z * sCz;

  const int NT = K >> 5;

  __shared__ short As[3][256 * 32];
  __shared__ short Bs[3][256 * 32];

  const int t = threadIdx.x;
  const int lane = t & 63;
  const int wave = t >> 6;
  const int wm = wave >> 2;
  const int wn = wave & 3;
  const int fr = lane & 15, kh = lane >> 4;
  const int koff = ((kh ^ ((fr >> 1) & 3)) << 3);

  int srow[2], scol[2];
  #pragma unroll
  for (int j = 0; j < 2; j++) {
    int e = j * 512 + t;
    srow[j] = e >> 2;
    scol[j] = (((e & 3) ^ ((e >> 3) & 3)) << 3);
  }

  f32x4 acc[8][4];
  #pragma unroll
  for (int i = 0; i < 8; i++)
    #pragma unroll
    for (int j = 0; j < 4; j++) acc[i][j] = (f32x4){0.f, 0.f, 0.f, 0.f};

  auto STAGE_A = [&](int kt) {
    const int buf = kt % 3, k0 = kt * 32;
    #pragma unroll
    for (int j = 0; j < 2; j++) {
      const short* pa = A + (size_t)(by * 256 + srow[j]) * lda + k0 + scol[j];
      GLDS(pa, (char*)&As[buf][0] + j * 8192 + wave * 1024);
    }
  };
  auto STAGE_B = [&](int kt) {
    const int buf = kt % 3, k0 = kt * 32;
    #pragma unroll
    for (int j = 0; j < 2; j++) {
      const short* pb = B + (size_t)(bx * 256 + srow[j]) * ldb + k0 + scol[j];
      GLDS(pb, (char*)&Bs[buf][0] + j * 8192 + wave * 1024);
    }
  };

  STAGE_A(0); STAGE_B(0);
  STAGE_A(1); STAGE_B(1);
  asm volatile("s_waitcnt vmcnt(4)\ns_barrier" ::: "memory");

  const int arow = wm * 128 + fr;
  const int brow = wn * 64 + fr;

  for (int kt = 0; kt < NT; kt++) {
    const short* as = &As[kt % 3][0];
    const short* bs = &Bs[kt % 3][0];
    short8 af[4], bfr[4];

    #pragma unroll
    for (int n = 0; n < 4; n++) bfr[n] = *(const short8*)&bs[(brow + n * 16) * 32 + koff];
    #pragma unroll
    for (int m = 0; m < 4; m++) af[m] = *(const short8*)&as[(arow + m * 16) * 32 + koff];
    if (kt + 2 < NT) STAGE_A(kt + 2);
    __builtin_amdgcn_s_barrier();
    asm volatile("s_waitcnt lgkmcnt(0)" ::: "memory");
    __builtin_amdgcn_sched_barrier(0);
    __builtin_amdgcn_s_setprio(1);
    #pragma unroll
    for (int m = 0; m < 4; m++)
      #pragma unroll
      for (int n = 0; n < 4; n++)
        acc[m][n] = __builtin_amdgcn_mfma_f32_16x16x32_bf16(af[m], bfr[n], acc[m][n], 0, 0, 0);
    __builtin_amdgcn_s_setprio(0);
    __builtin_amdgcn_sched_barrier(0);

    #pragma unroll
    for (int m = 0; m < 4; m++) af[m] = *(const short8*)&as[(arow + (m + 4) * 16) * 32 + koff];
    if (kt + 2 < NT) STAGE_B(kt + 2);
    __builtin_amdgcn_s_barrier();
    asm volatile("s_waitcnt lgkmcnt(0)" ::: "memory");
    __builtin_amdgcn_sched_barrier(0);
    __builtin_amdgcn_s_setprio(1);
    #pragma unroll
    for (int m = 0; m < 4; m++)
      #pragma unroll
      for (int n = 0; n < 4; n++)
        acc[m + 4][n] = __builtin_amdgcn_mfma_f32_16x16x32_bf16(af[m], bfr[n], acc[m + 4][n], 0, 0, 0);
    __builtin_amdgcn_s_setprio(0);
    __builtin_amdgcn_sched_barrier(0);

    if (kt + 2 < NT)      asm volatile("s_waitcnt vmcnt(4)\ns_barrier" ::: "memory");
    else if (kt + 1 < NT) asm volatile("s_waitcnt vmcnt(0)\ns_barrier" ::: "memory");
  }

  #pragma unroll
  for (int m = 0; m < 8; m++)
    #pragma unroll
    for (int n = 0; n < 4; n++) {
      int col_l = wn * 64 + n * 16 + fr;
      #pragma unroll
      for (int r = 0; r < 4; r++) {
        int row_l = wm * 128 + m * 16 + kh * 4 + r;
        if constexpr (MODE == 1)
          store_out(C, (size_t)(tri_by + bx) * 65536 + (size_t)row_l * 256 + col_l,
                    acc[m][n][r] * scale);
        else
          store_out(C, (size_t)(by * 256 + row_l) * ldc + bx * 256 + col_l,
                    acc[m][n][r] * scale);
      }
    }
}

// ---------------------------------------------------------------------------
// PV statically balanced: grid 256, EVERY block 8-9 units (64-72 ksteps) —
// no scheduler assumptions (r19/r20 failed relying on co-residency/greedy).
// Per combo (bx,z): slots 0-7 = 9-unit head of by 8-15 -> Out; slot 8 = by 7
// whole -> Out; slots 9-15 = {tail of by (24-slot) -> Ppart} + {by (slot-9)
// whole -> Out}. Partial tiles (by 9-15) reduced by pv_reduce.
// ---------------------------------------------------------------------------
__global__ __launch_bounds__(512, 2) void gemm_pv_bal(
    const short* __restrict__ SP, const short* __restrict__ Vt,
    float* __restrict__ Out, float* __restrict__ Ppart)
{
  const int w = blockIdx.x;
  const int combo = w >> 4;              // 16 combos
  const int slot = w & 15;
  const int bx = combo & 3, z = combo >> 2;
  const short* Abase = SP + (size_t)z * 136 * 65536;

  __shared__ short As[3][256 * 32];
  __shared__ short Bs[3][256 * 32];

  const int t = threadIdx.x;
  const int lane = t & 63;
  const int wave = t >> 6;
  const int wm = wave >> 2;
  const int wn = wave & 3;
  const int fr = lane & 15, kh = lane >> 4;
  const int koff = ((kh ^ ((fr >> 1) & 3)) << 3);

  int srow[2], scol[2];
  #pragma unroll
  for (int j = 0; j < 2; j++) {
    int e = j * 512 + t;
    srow[j] = e >> 2;
    scol[j] = (((e & 3) ^ ((e >> 3) & 3)) << 3);
  }
  const int arow = wm * 128 + fr;
  const int brow = wn * 64 + fr;

  const int nchunk = (slot >= 9) ? 2 : 1;
  for (int c = 0; c < nchunk; c++) {
    // arithmetic slot decode (no runtime-indexed arrays)
    int by, u0, u1, pp;
    if (c == 1)            { by = slot - 9;  u0 = 0; u1 = slot - 8; pp = -1; }
    else if (slot < 8)     { by = 8 + slot;  u0 = 0; u1 = 9;        pp = -1; }
    else if (slot == 8)    { by = 7;         u0 = 0; u1 = 8;        pp = -1; }
    else                   { by = 24 - slot; u0 = 9; u1 = by + 1;   pp = slot - 9; }
    const int tri_by = (by * (by + 1)) >> 1;
    const int kt0 = u0 * 8, kt1 = u1 * 8;

    f32x4 acc[8][4];
    #pragma unroll
    for (int i = 0; i < 8; i++)
      #pragma unroll
      for (int j = 0; j < 4; j++) acc[i][j] = (f32x4){0.f, 0.f, 0.f, 0.f};

    auto STAGE_A = [&](int kt) {
      const int buf = kt % 3, k0 = kt * 32;
      #pragma unroll
      for (int j = 0; j < 2; j++) {
        const short* pa = Abase + (size_t)(tri_by + (k0 >> 8)) * 65536
                                + (size_t)srow[j] * 256 + (k0 & 255) + scol[j];
        GLDS(pa, (char*)&As[buf][0] + j * 8192 + wave * 1024);
      }
    };
    auto STAGE_B = [&](int kt) {
      const int buf = kt % 3, k0 = kt * 32;
      #pragma unroll
      for (int j = 0; j < 2; j++) {
        const short* pb = Vt + (size_t)(bx * 256 + srow[j]) * 16384 + z * 4096 + k0 + scol[j];
        GLDS(pb, (char*)&Bs[buf][0] + j * 8192 + wave * 1024);
      }
    };

    STAGE_A(kt0); STAGE_B(kt0);
    STAGE_A(kt0 + 1); STAGE_B(kt0 + 1);
    asm volatile("s_waitcnt vmcnt(4)\ns_barrier" ::: "memory");

    for (int kt = kt0; kt < kt1; kt++) {
      const short* as = &As[kt % 3][0];
      const short* bs = &Bs[kt % 3][0];
      short8 af[4], bfr[4];

      #pragma unroll
      for (int n = 0; n < 4; n++) bfr[n] = *(const short8*)&bs[(brow + n * 16) * 32 + koff];
      #pragma unroll
      for (int m = 0; m < 4; m++) af[m] = *(const short8*)&as[(arow + m * 16) * 32 + koff];
      if (kt + 2 < kt1) STAGE_A(kt + 2);
      __builtin_amdgcn_s_barrier();
      asm volatile("s_waitcnt lgkmcnt(0)" ::: "memory");
      __builtin_amdgcn_sched_barrier(0);
      __builtin_amdgcn_s_setprio(1);
      #pragma unroll
      for (int m = 0; m < 4; m++)
        #pragma unroll
        for (int n = 0; n < 4; n++)
          acc[m][n] = __builtin_amdgcn_mfma_f32_16x16x32_bf16(af[m], bfr[n], acc[m][n], 0, 0, 0);
      __builtin_amdgcn_s_setprio(0);
      __builtin_amdgcn_sched_barrier(0);

      #pragma unroll
      for (int m = 0; m < 4; m++) af[m] = *(const short8*)&as[(arow + (m + 4) * 16) * 32 + koff];
      if (kt + 2 < kt1) STAGE_B(kt + 2);
      __builtin_amdgcn_s_barrier();
      asm volatile("s_waitcnt lgkmcnt(0)" ::: "memory");
      __builtin_amdgcn_sched_barrier(0);
      __builtin_amdgcn_s_setprio(1);
      #pragma unroll
      for (int m = 0; m < 4; m++)
        #pragma unroll
        for (int n = 0; n < 4; n++)
          acc[m + 4][n] = __builtin_amdgcn_mfma_f32_16x16x32_bf16(af[m], bfr[n], acc[m + 4][n], 0, 0, 0);
      __builtin_amdgcn_s_setprio(0);
      __builtin_amdgcn_sched_barrier(0);

      if (kt + 2 < kt1)      asm volatile("s_waitcnt vmcnt(4)\ns_barrier" ::: "memory");
      else                   asm volatile("s_waitcnt vmcnt(0)\ns_barrier" ::: "memory");
    }

    #pragma unroll
    for (int m = 0; m < 8; m++)
      #pragma unroll
      for (int n = 0; n < 4; n++) {
        int col_l = wn * 64 + n * 16 + fr;
        #pragma unroll
        for (int r = 0; r < 4; r++) {
          int row_l = wm * 128 + m * 16 + kh * 4 + r;
          if (pp >= 0)
            Ppart[(size_t)(combo * 7 + pp) * 65536 + (size_t)row_l * 256 + col_l] = acc[m][n][r];
          else
            Out[(size_t)z * 4096 * 1024 + (size_t)(by * 256 + row_l) * 1024
                + bx * 256 + col_l] = acc[m][n][r];
        }
      }
    __builtin_amdgcn_s_barrier();   // LDS ring safe before next chunk
  }
}

// Out += Ppart for the 112 partial tiles. Grid (112, 8): 32 rows each.
__global__ __launch_bounds__(256) void pv_reduce(
    const float* __restrict__ Ppart, float* __restrict__ Out)
{
  const int u = blockIdx.x;
  const int rg = blockIdx.y;
  const int combo = u / 7, p = u % 7;
  const int by = 15 - p, bx = combo & 3, z = combo >> 2;
  const int t = threadIdx.x;
  const float* src = Ppart + (size_t)u * 65536 + (size_t)rg * 32 * 256;
  float* dst = Out + (size_t)z * 4096 * 1024
                   + (size_t)(by * 256 + rg * 32) * 1024 + bx * 256;
  for (int i = t * 4; i < 8192; i += 1024) {
    int row = i >> 8, col = i & 255;
    f32x4 a = *(const f32x4*)&src[i];
    float* d = &dst[(size_t)row * 1024 + col];
    f32x4 b = *(const f32x4*)d;
    b[0] += a[0]; b[1] += a[1]; b[2] += a[2]; b[3] += a[3];
    *(f32x4*)d = b;
  }
}

// ---------------------------------------------------------------------------
// Small 128x128 GEMM (round-3 proven loop) — only for W2T = Wk^T.Wq (8x8).
// ---------------------------------------------------------------------------
__global__ __launch_bounds__(256) void gemm128(
    const short* __restrict__ A, int lda,
    const short* __restrict__ B, int ldb,
    bf16* __restrict__ C, int ldc, int K, float scale)
{
  const int bx = blockIdx.x, by = blockIdx.y;
  __shared__ short a_lds[128 * 32];
  __shared__ short b_lds[128 * 32];

  const int t = threadIdx.x;
  const int lane = t & 63;
  const int wave = t >> 6;
  const int wm = wave >> 1, wn = wave & 1;
  const int fr = lane & 15, kh = lane >> 4;

  f32x4 acc[4][4];
  #pragma unroll
  for (int i = 0; i < 4; i++)
    #pragma unroll
    for (int j = 0; j < 4; j++) acc[i][j] = (f32x4){0.f, 0.f, 0.f, 0.f};

  for (int k0 = 0; k0 < K; k0 += 32) {
    #pragma unroll
    for (int i = 0; i < 2; i++) {
      int e = i * 256 + t;
      int r_ = e >> 2, c_ = (e & 3) * 8;
      GLDS(A + (size_t)(by * 128 + r_) * lda + k0 + c_, (char*)a_lds + i * 4096 + wave * 1024);
      GLDS(B + (size_t)(bx * 128 + r_) * ldb + k0 + c_, (char*)b_lds + i * 4096 + wave * 1024);
    }
    __syncthreads();

    short8 af[4], bfr[4];
    #pragma unroll
    for (int m = 0; m < 4; m++)
      af[m] = *(const short8*)&a_lds[(wm * 64 + m * 16 + fr) * 32 + kh * 8];
    #pragma unroll
    for (int n = 0; n < 4; n++)
      bfr[n] = *(const short8*)&b_lds[(wn * 64 + n * 16 + fr) * 32 + kh * 8];
    #pragma unroll
    for (int m = 0; m < 4; m++)
      #pragma unroll
      for (int n = 0; n < 4; n++)
        acc[m][n] = __builtin_amdgcn_mfma_f32_16x16x32_bf16(af[m], bfr[n], acc[m][n], 0, 0, 0);
    __syncthreads();
  }

  #pragma unroll
  for (int m = 0; m < 4; m++)
    #pragma unroll
    for (int n = 0; n < 4; n++) {
      int col = bx * 128 + wn * 64 + n * 16 + fr;
      #pragma unroll
      for (int r = 0; r < 4; r++) {
        int row = by * 128 + wm * 64 + m * 16 + kh * 4 + r;
        C[(size_t)row * ldc + col] = __float2bfloat16(acc[m][n][r] * scale);
      }
    }
}

// fp32 -> bf16 elementwise convert with scale
__global__ __launch_bounds__(256) void cvt_bf16(
    const float* __restrict__ in, bf16* __restrict__ out, int n, float scale)
{
  for (int i = (blockIdx.x * 256 + threadIdx.x) * 8; i < n; i += gridDim.x * 2048) {
    f32x4 v0 = *(const f32x4*)&in[i];
    f32x4 v1 = *(const f32x4*)&in[i + 4];
    short8 o = { f2bfbits(v0[0] * scale), f2bfbits(v0[1] * scale),
                 f2bfbits(v0[2] * scale), f2bfbits(v0[3] * scale),
                 f2bfbits(v1[0] * scale), f2bfbits(v1[1] * scale),
                 f2bfbits(v1[2] * scale), f2bfbits(v1[3] * scale) };
    *(short8*)&out[i] = o;
  }
}

// fp32 (N x N) -> bf16 transposed (N x N): out[c][r] = in[r][c]. 64x64 tiles.
__global__ __launch_bounds__(256) void cvt_t_bf16(
    const float* __restrict__ in, bf16* __restrict__ out, int N)
{
  __shared__ float tile[64][65];
  const int bx = blockIdx.x, by = blockIdx.y;
  const int t = threadIdx.x;
  #pragma unroll
  for (int i = 0; i < 16; i++) {
    int e = i * 256 + t;
    int r = e >> 6, c = e & 63;
    tile[r][c] = in[(size_t)(by * 64 + r) * N + bx * 64 + c];
  }
  __syncthreads();
  #pragma unroll
  for (int i = 0; i < 16; i++) {
    int e = i * 256 + t;
    int r = e >> 6, c = e & 63;
    out[(size_t)(bx * 64 + r) * N + by * 64 + c] = __float2bfloat16(tile[c][r]);
  }
}

// In-place softmax on 256-packed block-triangular bf16 scores (vectorized).
__global__ __launch_bounds__(256) void softmax_causal_packed(short* SP, int T)
{
  __shared__ float rowv[4096];
  __shared__ float red[4];
  const int r = blockIdx.x;
  const int z = blockIdx.y;
  const int rb = r >> 8, rl = r & 255;
  const size_t tri = (size_t)((rb * (rb + 1)) >> 1);
  short* base = SP + (size_t)z * 136 * 65536;
  const int L = r + 1;
  const int kend = (rb + 1) * 256;
  const int t = threadIdx.x;

  float lmax = -3.0e38f;
  for (int i = t * 8; i < kend; i += 2048) {
    short8 s = *(const short8*)(base + (tri + (i >> 8)) * 65536 + (size_t)rl * 256 + (i & 255));
    #pragma unroll
    for (int j = 0; j < 8; j++) {
      float v = bf2f(s[j]);
      rowv[i + j] = v;
      if (i + j < L) lmax = fmaxf(lmax, v);
    }
  }
  #pragma unroll
  for (int o = 32; o > 0; o >>= 1) lmax = fmaxf(lmax, __shfl_down(lmax, o));
  if ((t & 63) == 0) red[t >> 6] = lmax;
  __syncthreads();
  const float m = fmaxf(fmaxf(red[0], red[1]), fmaxf(red[2], red[3]));
  __syncthreads();

  float lsum = 0.f;
  for (int i = t * 4; i < kend; i += 1024) {
    f32x4 v = *(const f32x4*)&rowv[i];
    f32x4 e;
    #pragma unroll
    for (int j = 0; j < 4; j++)
      e[j] = (i + j < L) ? __expf(v[j] - m) : 0.f;
    *(f32x4*)&rowv[i] = e;
    lsum += e[0] + e[1] + e[2] + e[3];
  }
  #pragma unroll
  for (int o = 32; o > 0; o >>= 1) lsum += __shfl_down(lsum, o);
  if ((t & 63) == 0) red[t >> 6] = lsum;
  __syncthreads();
  const float inv = 1.f / (red[0] + red[1] + red[2] + red[3]);

  for (int i = t * 8; i < kend; i += 2048) {
    short8 o;
    #pragma unroll
    for (int j = 0; j < 8; j++) o[j] = f2bfbits(rowv[i + j] * inv);
    *(short8*)(base + (tri + (i >> 8)) * 65536 + (size_t)rl * 256 + (i & 255)) = o;
  }
}

extern "C" void kernel_launch(void* const* d_in, const int* in_sizes, int n_in,
                              void* d_out, int out_size, void* d_ws, size_t ws_size,
                              hipStream_t stream) {
  (void)in_sizes; (void)n_in; (void)out_size; (void)ws_size;
  const float* X  = (const float*)d_in[0];   // (B,T,E)
  const float* Wq = (const float*)d_in[1];   // (A,E)
  const float* Wk = (const float*)d_in[2];
  const float* Wv = (const float*)d_in[3];
  float* Out = (float*)d_out;                // (B,T,A) fp32

  const int Bn = 4, T = 4096, E = 1024, Ad = 1024;
  const int M = Bn * T;  // 16384

  // Algebra: S = X.(Wq^T Wk / 32).X^T  — K-projection eliminated
  char* ws = (char*)d_ws;
  short* Q2  = (short*)ws;                    // [0,32Mi)   M x 1024 (dead after S)
  short* Vt  = (short*)(ws + 33554432);       // [32,64Mi)  Ad x M
  short* Xb  = (short*)(ws + 67108864);       // [64,96Mi)  M x E
  short* WqT = (short*)(ws + 100663296);      // E x A
  short* WkT = (short*)(ws + 102760448);
  short* Wvb = (short*)(ws + 104857600);
  short* W2T = (short*)(ws + 106954752);
  short* SP  = (short*)(ws + 109051904);      // 4 x 136 x 256x256 bf16
  float* Ppart = (float*)ws;                  // aliases dead Q2: 112 x 64K f32 = 28 MiB

  dim3 blk(256), blk5(512);
  const size_t SPz = (size_t)136 * 65536;

  // conversions
  cvt_bf16<<<dim3(8192), blk, 0, stream>>>(X, (bf16*)Xb, M * E, 1.0f);
  cvt_t_bf16<<<dim3(16, 16), blk, 0, stream>>>(Wq, (bf16*)WqT, E);
  cvt_t_bf16<<<dim3(16, 16), blk, 0, stream>>>(Wk, (bf16*)WkT, E);
  cvt_bf16<<<dim3(512), blk, 0, stream>>>(Wv, (bf16*)Wvb, Ad * E, 1.0f);

  // W2T[e2][e1] = sum_a Wk[a][e2]*Wq[a][e1] / 32
  gemm128<<<dim3(8, 8), blk, 0, stream>>>(
      WkT, Ad, WqT, Ad, (bf16*)W2T, E, Ad, 0.03125f);

  // Q2 (M x 1024) = Xb . W2T^T
  gemm256<bf16, 0><<<dim3(1024 / 256, M / 256), blk5, 0, stream>>>(
      Xb, E, 0, W2T, E, 0, (bf16*)Q2, 1024, 0, E, 1.0f);

  // all-batch V^T: Vt (Ad x M) = Wvb . Xb^T
  gemm256<bf16, 0><<<dim3(M / 256, Ad / 256), blk5, 0, stream>>>(
      Wvb, E, 0, Xb, E, 0, (bf16*)Vt, M, 0, E, 1.0f);

  // S (256-packed tri, all batches) = Q2 . Xb^T
  gemm256<bf16, 1><<<dim3(136, 1, Bn), blk5, 0, stream>>>(
      Q2, 1024, (size_t)T * 1024,
      Xb, 1024, (size_t)T * 1024,
      (bf16*)SP, 256, SPz, E, 1.0f);

  // in-place softmax on packed scores (all batches)
  softmax_causal_packed<<<dim3(T, Bn), blk, 0, stream>>>(SP, T);

  // O = P.V — statically balanced: 256 blocks x 8-9 units each
  gemm_pv_bal<<<dim3(256), blk5, 0, stream>>>(SP, Vt, Out, Ppart);
  // Out += Ppart for the 112 partial tiles
  pv_reduce<<<dim3(112, 8), blk, 0, stream>>>(Ppart, Out);
}